// Round 11
// baseline (296.862 us; speedup 1.0000x reference)
//
#include <hip/hip_runtime.h>
#include <hip/hip_bf16.h>
#include <cstdint>

#define B_ 4
#define T_ 2048
#define C_ 1024
#define H_ 16
#define D_ 64

// GEMM tile geometry (both GEMMs): 128x128, BK=64, 4 waves (2M x 2N), 64x64/wave
// SINGLE-buffer LDS (A 16K + B 16K = 32 KiB) -> 4-5 independent blocks/CU.
// Session evidence (R4 GEMM, R7-vs-R9 attn): resident independent blocks are
// the latency-hiding mechanism; drain-per-tile is acceptable when >=4 blocks
// interleave. 2-block dbuf measured 32% MfmaUtil (m97-ceiling); this trades
// the prefetch for +2-3 blocks of cross-block overlap.
#define BM 128
#define BN 128
#define BK 64
#define NT (C_ / BK)   // 16

typedef __bf16 bf16x8 __attribute__((ext_vector_type(8)));
typedef float f32x4 __attribute__((ext_vector_type(4)));

static __device__ __forceinline__ unsigned short f2bf(float f) {
    unsigned int i = __float_as_uint(f);
    unsigned int r = (i + 0x7FFFu + ((i >> 16) & 1u)) >> 16;
    return (unsigned short)r;
}
// native single-instruction bf16 convert (RTNE on gfx950)
static __device__ __forceinline__ unsigned short f2bf_hw(float f) {
    __bf16 h = (__bf16)f;
    union { __bf16 h; unsigned short u; } cv;
    cv.h = h;
    return cv.u;
}
static __device__ __forceinline__ float exp2_fast(float x) {
    float r;
    asm("v_exp_f32 %0, %1" : "=v"(r) : "v"(x));
    return r;
}
// packed f32x2 -> bf16x2 (one instruction; lo = s0, hi = s1)
static __device__ __forceinline__ unsigned int cvt_pk_bf16(float a, float b) {
    unsigned int r;
    asm("v_cvt_pk_bf16_f32 %0, %1, %2" : "=v"(r) : "v"(a), "v"(b));
    return r;
}

// async global->LDS, 16B per lane (HW: LDS dest = wave-uniform base + lane*16)
static __device__ __forceinline__ void gl_lds16(const unsigned short* g,
                                                unsigned short* l) {
    __builtin_amdgcn_global_load_lds(
        (const __attribute__((address_space(1))) unsigned int*)g,
        (__attribute__((address_space(3))) unsigned int*)l, 16, 0, 0);
}

// ---------------------------------------------------------------------------
// One-time prep: fp32 -> bf16 convert (n % 8 == 0)
// ---------------------------------------------------------------------------
__global__ __launch_bounds__(256)
void convert_f32_bf16(const float* __restrict__ in,
                      unsigned short* __restrict__ out, int n) {
    int i = (blockIdx.x * 256 + threadIdx.x) * 8;
    if (i < n) {
        float4 a = *(const float4*)(in + i);
        float4 b = *(const float4*)(in + i + 4);
        ushort4 s0 = {f2bf(a.x), f2bf(a.y), f2bf(a.z), f2bf(a.w)};
        ushort4 s1 = {f2bf(b.x), f2bf(b.y), f2bf(b.z), f2bf(b.w)};
        *(ushort4*)(out + i) = s0;
        *(ushort4*)(out + i + 4) = s1;
    }
}

// ---------------------------------------------------------------------------
// One-time prep: fp32 [R][Cc] -> bf16 [Cc][R] transpose
// ---------------------------------------------------------------------------
__global__ void transpose_f32_bf16(const float* __restrict__ in,
                                   unsigned short* __restrict__ out,
                                   int R, int Cc) {
    __shared__ unsigned short tile[32][33];
    int c0 = blockIdx.x * 32;
    int r0 = blockIdx.y * 32;
    int tx = threadIdx.x, ty = threadIdx.y;
    #pragma unroll
    for (int i = ty; i < 32; i += 8)
        tile[i][tx] = f2bf(in[(size_t)(r0 + i) * Cc + c0 + tx]);
    __syncthreads();
    #pragma unroll
    for (int i = ty; i < 32; i += 8)
        out[(size_t)(c0 + i) * R + r0 + tx] = tile[tx][i];
}

// ===========================================================================
// 128x128 GEMM core, SINGLE-buffer variant:
//   per K-tile: STAGE(t) -> vmcnt(0) -> s_barrier -> ds_read+MFMA -> s_barrier
//   (stage of t+1 cannot overlap compute of t within a block; 4-5 resident
//   independent blocks provide the overlap instead).
// XOR chunk swizzle both-sides (pre-swizzled global source at staging,
// swizzled chunk on ds_read) -> conflict-free ds_read_b128.
// LDS layout (u16): A at 0, B at 8192; row-major [128][64];
// phys chunk p holds logical chunk p^(row&7).
// ===========================================================================
#define GEMM128_CORE(APTR, ASTRIDE, BTPTR)                                    \
    int tid = threadIdx.x;                                                    \
    int nwg = gridDim.x * gridDim.y;                                          \
    int flat = blockIdx.y * gridDim.x + blockIdx.x;                           \
    int swz = (flat & 7) * (nwg >> 3) + (flat >> 3);                          \
    int bx = swz % gridDim.x;                                                 \
    int by = swz / gridDim.x;                                                 \
    int row0 = by * BM;                                                       \
    int col0 = bx * BN;                                                       \
    int wave = tid >> 6, lane = tid & 63;                                     \
    int wm = wave >> 1, wn = wave & 1;                                        \
    int m16 = lane & 15, quad = lane >> 4;                                    \
    int srow = tid >> 3;                                                      \
    int scs = ((tid & 7) ^ (srow & 7)) * 8;                                   \
    const unsigned short* aps = (APTR) + (size_t)(row0 + srow) * (ASTRIDE)    \
                                + scs;                                        \
    const unsigned short* bps = (BTPTR) + (size_t)(col0 + srow) * C_ + scs;   \
    f32x4 acc[4][4];                                                          \
    _Pragma("unroll")                                                         \
    for (int i = 0; i < 4; ++i)                                               \
    _Pragma("unroll")                                                         \
    for (int j = 0; j < 4; ++j)                                               \
        acc[i][j] = (f32x4){0.f, 0.f, 0.f, 0.f};                              \
    auto STAGE = [&](int t) {                                                 \
        int koff = t * BK;                                                    \
        unsigned short* ad = smem + tid * 8;                                  \
        unsigned short* bd = smem + 8192 + tid * 8;                           \
        _Pragma("unroll")                                                     \
        for (int l = 0; l < 4; ++l) {                                         \
            gl_lds16(aps + (size_t)(l * 32) * (ASTRIDE) + koff, ad + l * 2048);\
            gl_lds16(bps + (size_t)(l * 32) * C_ + koff, bd + l * 2048);      \
        }                                                                     \
    };                                                                        \
    int rbA = wm * 64 + m16;                                                  \
    int rbB = wn * 64 + m16;                                                  \
    int pc0 = ((0 + quad) ^ (m16 & 7)) * 8;                                   \
    int pc1 = ((4 + quad) ^ (m16 & 7)) * 8;                                   \
    for (int t = 0; t < NT; ++t) {                                            \
        STAGE(t);                                                             \
        asm volatile("s_waitcnt vmcnt(0)" ::: "memory");                      \
        __builtin_amdgcn_s_barrier();                                         \
        const unsigned short* Abuf = smem;                                    \
        const unsigned short* Bbuf = smem + 8192;                             \
        bf16x8 a0[4], a1[4], b0[4], b1[4];                                    \
        _Pragma("unroll")                                                     \
        for (int i = 0; i < 4; ++i) {                                         \
            a0[i] = *(const bf16x8*)(Abuf + (rbA + i * 16) * 64 + pc0);       \
            a1[i] = *(const bf16x8*)(Abuf + (rbA + i * 16) * 64 + pc1);       \
        }                                                                     \
        _Pragma("unroll")                                                     \
        for (int j = 0; j < 4; ++j) {                                         \
            b0[j] = *(const bf16x8*)(Bbuf + (rbB + j * 16) * 64 + pc0);       \
            b1[j] = *(const bf16x8*)(Bbuf + (rbB + j * 16) * 64 + pc1);       \
        }                                                                     \
        __builtin_amdgcn_s_setprio(1);                                        \
        _Pragma("unroll")                                                     \
        for (int i = 0; i < 4; ++i)                                           \
        _Pragma("unroll")                                                     \
        for (int j = 0; j < 4; ++j) {                                         \
            acc[i][j] = __builtin_amdgcn_mfma_f32_16x16x32_bf16(              \
                a0[i], b0[j], acc[i][j], 0, 0, 0);                            \
            acc[i][j] = __builtin_amdgcn_mfma_f32_16x16x32_bf16(              \
                a1[i], b1[j], acc[i][j], 0, 0, 0);                            \
        }                                                                     \
        __builtin_amdgcn_s_setprio(0);                                        \
        __builtin_amdgcn_s_barrier();                                         \
    }                                                                         \
    __syncthreads();

// ---------------------------------------------------------------------------
// GEMM1 (fused): [M x 3C] = A[M][C] @ w_attn_t[3C][C]^T + b_attn
// ---------------------------------------------------------------------------
__global__ __launch_bounds__(256, 4)
void gemm_qkv(const unsigned short* __restrict__ A,
              const unsigned short* __restrict__ Bt,
              const float* __restrict__ bias,
              unsigned short* __restrict__ qkv,
              unsigned short* __restrict__ vt,
              int M, float qscale) {
    __shared__ __align__(16) unsigned short smem[16384];   // 32 KiB
    GEMM128_CORE(A, C_, Bt)

    // ---- epilogue (per-wave 64x64 tile via wave-private LDS roundtrip) ----
    float bv[4];
    #pragma unroll
    for (int j = 0; j < 4; ++j)
        bv[j] = bias[col0 + wn * 64 + j * 16 + m16];

    unsigned short* wbuf = smem + wave * 2048;   // 4 KiB per wave, 4 waves
    bool isV = (col0 >= 2 * C_);
    float sc = (col0 < C_) ? qscale : 1.0f;
    int b_loc = row0 >> 11;            // batch index (T=2048, 128 | T)
    int trow0 = (row0 & 2047) + wm * 64;
    int head = isV ? ((col0 - 2 * C_ + wn * 64) >> 6) : 0;
    unsigned short* vtb = vt + (size_t)((b_loc * H_ + head) * 64) * T_;

    #pragma unroll
    for (int sub = 0; sub < 4; ++sub) {
        int i0 = (sub >> 1) << 1;      // 0,0,2,2
        int j0 = (sub & 1) << 1;       // 0,2,0,2
        #pragma unroll
        for (int jj = 0; jj < 2; ++jj) {
            #pragma unroll
            for (int ii = 0; ii < 2; ++ii) {
                #pragma unroll
                for (int rr = 0; rr < 4; ++rr) {
                    int rl = ii * 16 + quad * 4 + rr;
                    int cl = jj * 16 + m16;
                    unsigned short hv =
                        f2bf((acc[i0 + ii][j0 + jj][rr] + bv[j0 + jj]) * sc);
                    if (!isV) wbuf[rl * 40 + cl] = hv;      // [row][col]
                    else      wbuf[cl * 40 + rl] = hv;      // [col][row]
                }
            }
        }
        __builtin_amdgcn_sched_barrier(0);
        if (!isV) {
            #pragma unroll
            for (int it = 0; it < 4; ++it) {
                int rl = it * 8 + (lane >> 3);
                int cc = (lane & 7) << 2;
                uint2 v2 = *(const uint2*)&wbuf[rl * 40 + cc];
                int rowg = row0 + wm * 64 + i0 * 16 + rl;
                int colg = col0 + wn * 64 + j0 * 16 + cc;
                *(uint2*)&qkv[(size_t)rowg * (2 * C_) + colg] = v2;
            }
        } else {
            #pragma unroll
            for (int it = 0; it < 4; ++it) {
                int dsub = it * 8 + (lane >> 3);
                int tc = (lane & 7) << 2;
                uint2 v2 = *(const uint2*)&wbuf[dsub * 40 + tc];
                int d = j0 * 16 + dsub;
                int tg = trow0 + i0 * 16 + tc;
                *(uint2*)&vtb[(size_t)d * T_ + tg] = v2;
            }
        }
        __builtin_amdgcn_sched_barrier(0);
    }
}

// ---------------------------------------------------------------------------
// GEMM2: out[M][C] (fp32) = A[M][K=C] (bf16, row stride 2C) @ w_proj_t^T + b
// ---------------------------------------------------------------------------
__global__ __launch_bounds__(256, 4)
void gemm_out(const unsigned short* __restrict__ A,
              const unsigned short* __restrict__ Bt,
              const float* __restrict__ bias,
              float* __restrict__ Cmat,
              int M) {
    const int N = C_;
    __shared__ __align__(16) unsigned short smem[16384];
    GEMM128_CORE(A, (2 * C_), Bt)

    #pragma unroll
    for (int j = 0; j < 4; ++j) {
        int col = col0 + wn * 64 + j * 16 + m16;
        float bvv = bias[col];
        #pragma unroll
        for (int i = 0; i < 4; ++i) {
            int row = row0 + wm * 64 + i * 16 + quad * 4;
            #pragma unroll
            for (int rr = 0; rr < 4; ++rr)
                Cmat[(size_t)(row + rr) * N + col] = acc[i][j][rr] + bvv;
        }
    }
}

// ---------------------------------------------------------------------------
// MFMA causal flash attention, swapped-QK in-register-P variant (R10, won).
// ---------------------------------------------------------------------------
__global__ __launch_bounds__(256, 3)
void attn_mfma(unsigned short* __restrict__ qkv,
               const unsigned short* __restrict__ vt) {
    __shared__ __align__(16) unsigned short Ks[2][64][64];    // 16 KiB [buf][key][d]
    __shared__ __align__(16) unsigned short Vs[2][64][64];    // 16 KiB [buf][d][key]
    __shared__ __align__(16) unsigned short P2[4][2][16][64]; // 16 KiB per-wave P scratch

    int bh = blockIdx.x;
    int b = bh >> 4, h = bh & 15;
    int qb = (T_ / 128 - 1) - blockIdx.y;    // 0..15 reversed: big blocks first
    int tid = threadIdx.x;
    int wave = tid >> 6;
    int lane = tid & 63;
    int m16 = lane & 15, quad = lane >> 4;

    const size_t rs = 2 * C_;
    unsigned short* base = qkv + (size_t)b * T_ * rs + h * 64;
    const unsigned short* kb0 = base + C_;
    const unsigned short* vtb = vt + (size_t)bh * 64 * T_;

    // Q: two 16-row fragments per wave (rows qb*128 + wave*32 + f*16 + m16)
    bf16x8 qf0[2], qf1[2];
    #pragma unroll
    for (int f = 0; f < 2; ++f) {
        int qrow = qb * 128 + wave * 32 + f * 16 + m16;
        const unsigned short* qp = base + (size_t)qrow * rs;
        qf0[f] = *(const bf16x8*)(qp + quad * 8);
        qf1[f] = *(const bf16x8*)(qp + 32 + quad * 8);
    }

    f32x4 o[2][4];
    #pragma unroll
    for (int f = 0; f < 2; ++f)
        #pragma unroll
        for (int dt = 0; dt < 4; ++dt) o[f][dt] = (f32x4){0.f, 0.f, 0.f, 0.f};
    float lrow[2] = {0.f, 0.f};          // denominator partial for q = m16

    int qbase = qb * 128 + wave * 32;
    int ntiles = 2 * qb + 2;             // always >= 2

    // staging: row = tid>>3 (0..31) and +32; pre-swizzled global source
    int srow = tid >> 3;
    int schs = ((tid & 7) ^ (srow & 7)) * 8;
    const unsigned short* kps = kb0 + (size_t)srow * rs + schs;
    const unsigned short* vps = vtb + (size_t)srow * T_ + schs;
    unsigned short* kdst = &Ks[0][0][0] + wave * 512;   // +buf*4096 u16
    unsigned short* vdst = &Vs[0][0][0] + wave * 512;

    auto STAGE = [&](int kt, int buf) {
        const unsigned short* ks = kps + (size_t)(kt * 64) * rs;
        const unsigned short* vs = vps + kt * 64;
        unsigned short* kd = kdst + buf * 4096;
        unsigned short* vd = vdst + buf * 4096;
        gl_lds16(ks, kd);
        gl_lds16(ks + (size_t)32 * rs, kd + 2048);
        gl_lds16(vs, vd);
        gl_lds16(vs + (size_t)32 * T_, vd + 2048);
    };

    // read-side swizzled chunk offsets (row&7 == m16&7 for all our rows)
    int kpc0 = ((0 + quad) ^ (m16 & 7)) << 3;
    int kpc1 = ((4 + quad) ^ (m16 & 7)) << 3;

    STAGE(0, 0);
    asm volatile("s_waitcnt vmcnt(0)" ::: "memory");
    __builtin_amdgcn_s_barrier();

    for (int kt = 0; kt < ntiles; ++kt) {
        int cur = kt & 1;
        if (kt + 1 < ntiles) STAGE(kt + 1, cur ^ 1);

        // ---- QK^T swapped: S^T[key][q]; lane: q = m16, key = st*16+quad*4+r
        f32x4 s[2][4];
        #pragma unroll
        for (int st = 0; st < 4; ++st) {
            bf16x8 k0 = *(const bf16x8*)&Ks[cur][st * 16 + m16][kpc0];
            bf16x8 k1 = *(const bf16x8*)&Ks[cur][st * 16 + m16][kpc1];
            __builtin_amdgcn_s_setprio(1);
            #pragma unroll
            for (int f = 0; f < 2; ++f) {
                f32x4 a = (f32x4){0.f, 0.f, 0.f, 0.f};
                a = __builtin_amdgcn_mfma_f32_16x16x32_bf16(k0, qf0[f], a, 0, 0, 0);
                a = __builtin_amdgcn_mfma_f32_16x16x32_bf16(k1, qf1[f], a, 0, 0, 0);
                s[f][st] = a;
            }
            __builtin_amdgcn_s_setprio(0);
        }

        // ---- causal mask (transposed indexing) ----
        if (kt >= 2 * qb) {
            #pragma unroll
            for (int f = 0; f < 2; ++f) {
                int qg = qbase + f * 16 + m16;
                #pragma unroll
                for (int st = 0; st < 4; ++st) {
                    int kg = kt * 64 + st * 16 + quad * 4;
                    #pragma unroll
                    for (int r = 0; r < 4; ++r)
                        if (kg + r > qg) s[f][st][r] = -1.0e30f;
                }
            }
        }

        // ---- exp2 + pack + scatter to P2 (16 cvt_pk + 16 b32 writes) ----
        #pragma unroll
        for (int f = 0; f < 2; ++f)
            #pragma unroll
            for (int st = 0; st < 4; ++st) {
                float p0 = exp2_fast(s[f][st][0]);
                float p1 = exp2_fast(s[f][st][1]);
                float p2 = exp2_fast(s[f][st][2]);
                float p3 = exp2_fast(s[f][st][3]);
                lrow[f] += (p0 + p1) + (p2 + p3);
                unsigned int d0 = cvt_pk_bf16(p0, p1);
                unsigned int d1 = cvt_pk_bf16(p2, p3);
                int pb = (st * 2 + (quad >> 1)) ^ (m16 & 7);
                int wd = (quad & 1) * 2;
                *(unsigned int*)&P2[wave][f][m16][pb * 8 + wd * 2]       = d0;
                *(unsigned int*)&P2[wave][f][m16][pb * 8 + (wd + 1) * 2] = d1;
            }
        __builtin_amdgcn_sched_barrier(0);

        // ---- PV: o[f] += P[f] @ V (pa read offset == V read offset) ----
        #pragma unroll
        for (int s2 = 0; s2 < 2; ++s2) {
            int pc = ((s2 * 4 + quad) ^ (m16 & 7)) << 3;
            #pragma unroll
            for (int f = 0; f < 2; ++f) {
                bf16x8 pa = *(const bf16x8*)&P2[wave][f][m16][pc];
                __builtin_amdgcn_s_setprio(1);
                #pragma unroll
                for (int dt = 0; dt < 4; ++dt) {
                    bf16x8 vv = *(const bf16x8*)&Vs[cur][dt * 16 + m16][pc];
                    o[f][dt] = __builtin_amdgcn_mfma_f32_16x16x32_bf16(
                        pa, vv, o[f][dt], 0, 0, 0);
                }
                __builtin_amdgcn_s_setprio(0);
            }
        }
        __builtin_amdgcn_sched_barrier(0);

        asm volatile("s_waitcnt vmcnt(0)" ::: "memory");
        __builtin_amdgcn_s_barrier();
    }

    // ---- finalize: quad-reduce denominators, redistribute, scale, store ----
    #pragma unroll
    for (int f = 0; f < 2; ++f) {
        float lf = lrow[f];
        lf += __shfl_xor(lf, 16);
        lf += __shfl_xor(lf, 32);          // full sum for q = m16 at every lane
        float inv = 1.0f / lf;
        #pragma unroll
        for (int r = 0; r < 4; ++r) {
            float invr = __shfl(inv, quad * 4 + r);   // inv for q-local quad*4+r
            unsigned short* op = base + (size_t)(qbase + f * 16 + quad * 4 + r) * rs;
            #pragma unroll
            for (int dt = 0; dt < 4; ++dt)
                op[dt * 16 + m16] = f2bf_hw(o[f][dt][r] * invr);
        }
    }
}

// ---------------------------------------------------------------------------
extern "C" void kernel_launch(void* const* d_in, const int* in_sizes, int n_in,
                              void* d_out, int out_size, void* d_ws, size_t ws_size,
                              hipStream_t stream) {
    const float* x      = (const float*)d_in[0];
    const float* w_attn = (const float*)d_in[1];
    const float* b_attn = (const float*)d_in[2];
    const float* w_proj = (const float*)d_in[3];
    const float* b_proj = (const float*)d_in[4];
    float* out = (float*)d_out;

    unsigned short* ws = (unsigned short*)d_ws;
    unsigned short* xb       = ws;                               // [B*T][C]
    unsigned short* w_attn_t = xb + (size_t)B_ * T_ * C_;        // [3C][C]
    unsigned short* w_proj_t = w_attn_t + (size_t)3 * C_ * C_;   // [C][C]
    unsigned short* qkv      = w_proj_t + (size_t)C_ * C_;       // [bstep*T][2C]

    const size_t fixed_hw = (size_t)B_ * T_ * C_ + 4 * (size_t)C_ * C_;
    const size_t per_b_hw = (size_t)T_ * 2 * C_ + (size_t)H_ * 64 * T_; // qk + vt
    int bstep = (ws_size >= (fixed_hw + (size_t)B_ * per_b_hw) * sizeof(unsigned short))
                ? B_ : 1;

    int nx = B_ * T_ * C_;
    convert_f32_bf16<<<nx / 2048, 256, 0, stream>>>(x, xb, nx);
    transpose_f32_bf16<<<dim3(3 * C_ / 32, C_ / 32), dim3(32, 8), 0, stream>>>(
        w_attn, w_attn_t, C_, 3 * C_);
    transpose_f32_bf16<<<dim3(C_ / 32, C_ / 32), dim3(32, 8), 0, stream>>>(
        w_proj, w_proj_t, C_, C_);

    // q pre-scale: (1/sqrt(D)) * log2(e)  -> softmax via exp2, no max-sub
    const float QSCALE = 0.125f * 1.44269504088896341f;

    for (int b0 = 0; b0 < B_; b0 += bstep) {
        int M = bstep * T_;
        const unsigned short* xbb = xb + (size_t)b0 * T_ * C_;
        unsigned short* vt = qkv + (size_t)bstep * T_ * 2 * C_;  // [bstep*H][64][T]

        gemm_qkv<<<dim3(3 * C_ / BN, M / BM), 256, 0, stream>>>(
            xbb, w_attn_t, b_attn, qkv, vt, M, QSCALE);

        attn_mfma<<<dim3(bstep * H_, T_ / 128), 256, 0, stream>>>(qkv, vt);

        gemm_out<<<dim3(C_ / BN, M / BM), 256, 0, stream>>>(
            qkv, w_proj_t, b_proj, out + (size_t)b0 * T_ * C_, M);
    }
}

// Round 12
// 244.911 us; speedup vs baseline: 1.2121x; 1.2121x over previous
//
#include <hip/hip_runtime.h>
#include <hip/hip_bf16.h>
#include <cstdint>

#define B_ 4
#define T_ 2048
#define C_ 1024
#define H_ 16
#define D_ 64

// GEMM tile geometry (both GEMMs): 128x128, BK=32, 4 waves (2M x 2N), 64x64/wave
// m97-verified structure: double-buffered LDS = 2 x (A 8K + B 8K) = 32 KiB
// -> prefetch AND 3-4 resident blocks/CU (912 TF ref-checked on MI355X).
// At BK=32 the LDS row stride is 64 B (16 banks): a wave's ds_read_b128
// spreads over all 32 banks at the 8-cycle floor -> NO swizzle needed.
#define BM 128
#define BN 128
#define BK 32
#define NT (C_ / BK)   // 32

typedef __bf16 bf16x8 __attribute__((ext_vector_type(8)));
typedef float f32x4 __attribute__((ext_vector_type(4)));

static __device__ __forceinline__ unsigned short f2bf(float f) {
    unsigned int i = __float_as_uint(f);
    unsigned int r = (i + 0x7FFFu + ((i >> 16) & 1u)) >> 16;
    return (unsigned short)r;
}
// native single-instruction bf16 convert (RTNE on gfx950)
static __device__ __forceinline__ unsigned short f2bf_hw(float f) {
    __bf16 h = (__bf16)f;
    union { __bf16 h; unsigned short u; } cv;
    cv.h = h;
    return cv.u;
}
static __device__ __forceinline__ float exp2_fast(float x) {
    float r;
    asm("v_exp_f32 %0, %1" : "=v"(r) : "v"(x));
    return r;
}
// packed f32x2 -> bf16x2 (one instruction; lo = s0, hi = s1)
static __device__ __forceinline__ unsigned int cvt_pk_bf16(float a, float b) {
    unsigned int r;
    asm("v_cvt_pk_bf16_f32 %0, %1, %2" : "=v"(r) : "v"(a), "v"(b));
    return r;
}

// async global->LDS, 16B per lane (HW: LDS dest = wave-uniform base + lane*16)
static __device__ __forceinline__ void gl_lds16(const unsigned short* g,
                                                unsigned short* l) {
    __builtin_amdgcn_global_load_lds(
        (const __attribute__((address_space(1))) unsigned int*)g,
        (__attribute__((address_space(3))) unsigned int*)l, 16, 0, 0);
}

// ---------------------------------------------------------------------------
// One-time prep: fp32 -> bf16 convert (n % 8 == 0)
// ---------------------------------------------------------------------------
__global__ __launch_bounds__(256)
void convert_f32_bf16(const float* __restrict__ in,
                      unsigned short* __restrict__ out, int n) {
    int i = (blockIdx.x * 256 + threadIdx.x) * 8;
    if (i < n) {
        float4 a = *(const float4*)(in + i);
        float4 b = *(const float4*)(in + i + 4);
        ushort4 s0 = {f2bf(a.x), f2bf(a.y), f2bf(a.z), f2bf(a.w)};
        ushort4 s1 = {f2bf(b.x), f2bf(b.y), f2bf(b.z), f2bf(b.w)};
        *(ushort4*)(out + i) = s0;
        *(ushort4*)(out + i + 4) = s1;
    }
}

// ---------------------------------------------------------------------------
// One-time prep: fp32 [R][Cc] -> bf16 [Cc][R] transpose
// ---------------------------------------------------------------------------
__global__ void transpose_f32_bf16(const float* __restrict__ in,
                                   unsigned short* __restrict__ out,
                                   int R, int Cc) {
    __shared__ unsigned short tile[32][33];
    int c0 = blockIdx.x * 32;
    int r0 = blockIdx.y * 32;
    int tx = threadIdx.x, ty = threadIdx.y;
    #pragma unroll
    for (int i = ty; i < 32; i += 8)
        tile[i][tx] = f2bf(in[(size_t)(r0 + i) * Cc + c0 + tx]);
    __syncthreads();
    #pragma unroll
    for (int i = ty; i < 32; i += 8)
        out[(size_t)(c0 + i) * R + r0 + tx] = tile[tx][i];
}

// ===========================================================================
// 128x128 GEMM core, BK=32 double-buffer (m97 geometry):
//   per K-tile: STAGE(t+1) -> 8 ds_read_b128 + 16 MFMA -> vmcnt(0) -> barrier
//   LDS 32 KiB -> 3-4 independent blocks/CU WITH prefetch.
// Linear layout [128][32] u16 (row stride 64 B): ds_read_b128 at the 8-cycle
// bank floor without swizzle; gl_lds dest = base + tid*16B (linear).
// LDS (u16): A(buf) at buf*4096, B(buf) at 8192 + buf*4096.
// ===========================================================================
#define GEMM128_CORE(APTR, ASTRIDE, BTPTR)                                    \
    int tid = threadIdx.x;                                                    \
    int nwg = gridDim.x * gridDim.y;                                          \
    int flat = blockIdx.y * gridDim.x + blockIdx.x;                           \
    int swz = (flat & 7) * (nwg >> 3) + (flat >> 3);                          \
    int bx = swz % gridDim.x;                                                 \
    int by = swz / gridDim.x;                                                 \
    int row0 = by * BM;                                                       \
    int col0 = bx * BN;                                                       \
    int wave = tid >> 6, lane = tid & 63;                                     \
    int wm = wave >> 1, wn = wave & 1;                                        \
    int m16 = lane & 15, quad = lane >> 4;                                    \
    int srow = tid >> 2;                                                      \
    int scol = (tid & 3) * 8;                                                 \
    const unsigned short* aps = (APTR) + (size_t)(row0 + srow) * (ASTRIDE)    \
                                + scol;                                       \
    const unsigned short* bps = (BTPTR) + (size_t)(col0 + srow) * C_ + scol;  \
    f32x4 acc[4][4];                                                          \
    _Pragma("unroll")                                                         \
    for (int i = 0; i < 4; ++i)                                               \
    _Pragma("unroll")                                                         \
    for (int j = 0; j < 4; ++j)                                               \
        acc[i][j] = (f32x4){0.f, 0.f, 0.f, 0.f};                              \
    auto STAGE = [&](int t, int buf) {                                        \
        int koff = t * BK;                                                    \
        unsigned short* ad = smem + buf * 4096 + tid * 8;                     \
        unsigned short* bd = smem + 8192 + buf * 4096 + tid * 8;              \
        _Pragma("unroll")                                                     \
        for (int l = 0; l < 2; ++l) {                                         \
            gl_lds16(aps + (size_t)(l * 64) * (ASTRIDE) + koff, ad + l * 2048);\
            gl_lds16(bps + (size_t)(l * 64) * C_ + koff, bd + l * 2048);      \
        }                                                                     \
    };                                                                        \
    int rbA = wm * 64 + m16;                                                  \
    int rbB = wn * 64 + m16;                                                  \
    int pcq = quad * 8;                                                       \
    STAGE(0, 0);                                                              \
    asm volatile("s_waitcnt vmcnt(0)" ::: "memory");                          \
    __builtin_amdgcn_s_barrier();                                             \
    for (int t = 0; t < NT; ++t) {                                            \
        int buf = t & 1;                                                      \
        if (t + 1 < NT) STAGE(t + 1, buf ^ 1);                                \
        const unsigned short* Abuf = smem + buf * 4096;                       \
        const unsigned short* Bbuf = smem + 8192 + buf * 4096;                \
        bf16x8 a0[4], b0[4];                                                  \
        _Pragma("unroll")                                                     \
        for (int i = 0; i < 4; ++i)                                           \
            a0[i] = *(const bf16x8*)(Abuf + (rbA + i * 16) * 32 + pcq);       \
        _Pragma("unroll")                                                     \
        for (int j = 0; j < 4; ++j)                                           \
            b0[j] = *(const bf16x8*)(Bbuf + (rbB + j * 16) * 32 + pcq);       \
        __builtin_amdgcn_s_setprio(1);                                        \
        _Pragma("unroll")                                                     \
        for (int i = 0; i < 4; ++i)                                           \
        _Pragma("unroll")                                                     \
        for (int j = 0; j < 4; ++j)                                           \
            acc[i][j] = __builtin_amdgcn_mfma_f32_16x16x32_bf16(              \
                a0[i], b0[j], acc[i][j], 0, 0, 0);                            \
        __builtin_amdgcn_s_setprio(0);                                        \
        asm volatile("s_waitcnt vmcnt(0)" ::: "memory");                      \
        __builtin_amdgcn_s_barrier();                                         \
    }                                                                         \
    __syncthreads();

// ---------------------------------------------------------------------------
// GEMM1 (fused): [M x 3C] = A[M][C] @ w_attn_t[3C][C]^T + b_attn
// ---------------------------------------------------------------------------
__global__ __launch_bounds__(256, 4)
void gemm_qkv(const unsigned short* __restrict__ A,
              const unsigned short* __restrict__ Bt,
              const float* __restrict__ bias,
              unsigned short* __restrict__ qkv,
              unsigned short* __restrict__ vt,
              int M, float qscale) {
    __shared__ __align__(16) unsigned short smem[16384];   // 32 KiB
    GEMM128_CORE(A, C_, Bt)

    // ---- epilogue (per-wave 64x64 tile via wave-private LDS roundtrip) ----
    float bv[4];
    #pragma unroll
    for (int j = 0; j < 4; ++j)
        bv[j] = bias[col0 + wn * 64 + j * 16 + m16];

    unsigned short* wbuf = smem + wave * 2048;   // 4 KiB per wave, 4 waves
    bool isV = (col0 >= 2 * C_);
    float sc = (col0 < C_) ? qscale : 1.0f;
    int b_loc = row0 >> 11;            // batch index (T=2048, 128 | T)
    int trow0 = (row0 & 2047) + wm * 64;
    int head = isV ? ((col0 - 2 * C_ + wn * 64) >> 6) : 0;
    unsigned short* vtb = vt + (size_t)((b_loc * H_ + head) * 64) * T_;

    #pragma unroll
    for (int sub = 0; sub < 4; ++sub) {
        int i0 = (sub >> 1) << 1;      // 0,0,2,2
        int j0 = (sub & 1) << 1;       // 0,2,0,2
        #pragma unroll
        for (int jj = 0; jj < 2; ++jj) {
            #pragma unroll
            for (int ii = 0; ii < 2; ++ii) {
                #pragma unroll
                for (int rr = 0; rr < 4; ++rr) {
                    int rl = ii * 16 + quad * 4 + rr;
                    int cl = jj * 16 + m16;
                    unsigned short hv =
                        f2bf((acc[i0 + ii][j0 + jj][rr] + bv[j0 + jj]) * sc);
                    if (!isV) wbuf[rl * 40 + cl] = hv;      // [row][col]
                    else      wbuf[cl * 40 + rl] = hv;      // [col][row]
                }
            }
        }
        __builtin_amdgcn_sched_barrier(0);
        if (!isV) {
            #pragma unroll
            for (int it = 0; it < 4; ++it) {
                int rl = it * 8 + (lane >> 3);
                int cc = (lane & 7) << 2;
                uint2 v2 = *(const uint2*)&wbuf[rl * 40 + cc];
                int rowg = row0 + wm * 64 + i0 * 16 + rl;
                int colg = col0 + wn * 64 + j0 * 16 + cc;
                *(uint2*)&qkv[(size_t)rowg * (2 * C_) + colg] = v2;
            }
        } else {
            #pragma unroll
            for (int it = 0; it < 4; ++it) {
                int dsub = it * 8 + (lane >> 3);
                int tc = (lane & 7) << 2;
                uint2 v2 = *(const uint2*)&wbuf[dsub * 40 + tc];
                int d = j0 * 16 + dsub;
                int tg = trow0 + i0 * 16 + tc;
                *(uint2*)&vtb[(size_t)d * T_ + tg] = v2;
            }
        }
        __builtin_amdgcn_sched_barrier(0);
    }
}

// ---------------------------------------------------------------------------
// GEMM2: out[M][C] (fp32) = A[M][K=C] (bf16, row stride 2C) @ w_proj_t^T + b
// ---------------------------------------------------------------------------
__global__ __launch_bounds__(256, 4)
void gemm_out(const unsigned short* __restrict__ A,
              const unsigned short* __restrict__ Bt,
              const float* __restrict__ bias,
              float* __restrict__ Cmat,
              int M) {
    const int N = C_;
    __shared__ __align__(16) unsigned short smem[16384];
    GEMM128_CORE(A, (2 * C_), Bt)

    #pragma unroll
    for (int j = 0; j < 4; ++j) {
        int col = col0 + wn * 64 + j * 16 + m16;
        float bvv = bias[col];
        #pragma unroll
        for (int i = 0; i < 4; ++i) {
            int row = row0 + wm * 64 + i * 16 + quad * 4;
            #pragma unroll
            for (int rr = 0; rr < 4; ++rr)
                Cmat[(size_t)(row + rr) * N + col] = acc[i][j][rr] + bvv;
        }
    }
}

// ---------------------------------------------------------------------------
// MFMA causal flash attention, swapped-QK in-register-P variant (R10, won).
// ---------------------------------------------------------------------------
__global__ __launch_bounds__(256, 3)
void attn_mfma(unsigned short* __restrict__ qkv,
               const unsigned short* __restrict__ vt) {
    __shared__ __align__(16) unsigned short Ks[2][64][64];    // 16 KiB [buf][key][d]
    __shared__ __align__(16) unsigned short Vs[2][64][64];    // 16 KiB [buf][d][key]
    __shared__ __align__(16) unsigned short P2[4][2][16][64]; // 16 KiB per-wave P scratch

    int bh = blockIdx.x;
    int b = bh >> 4, h = bh & 15;
    int qb = (T_ / 128 - 1) - blockIdx.y;    // 0..15 reversed: big blocks first
    int tid = threadIdx.x;
    int wave = tid >> 6;
    int lane = tid & 63;
    int m16 = lane & 15, quad = lane >> 4;

    const size_t rs = 2 * C_;
    unsigned short* base = qkv + (size_t)b * T_ * rs + h * 64;
    const unsigned short* kb0 = base + C_;
    const unsigned short* vtb = vt + (size_t)bh * 64 * T_;

    // Q: two 16-row fragments per wave (rows qb*128 + wave*32 + f*16 + m16)
    bf16x8 qf0[2], qf1[2];
    #pragma unroll
    for (int f = 0; f < 2; ++f) {
        int qrow = qb * 128 + wave * 32 + f * 16 + m16;
        const unsigned short* qp = base + (size_t)qrow * rs;
        qf0[f] = *(const bf16x8*)(qp + quad * 8);
        qf1[f] = *(const bf16x8*)(qp + 32 + quad * 8);
    }

    f32x4 o[2][4];
    #pragma unroll
    for (int f = 0; f < 2; ++f)
        #pragma unroll
        for (int dt = 0; dt < 4; ++dt) o[f][dt] = (f32x4){0.f, 0.f, 0.f, 0.f};
    float lrow[2] = {0.f, 0.f};          // denominator partial for q = m16

    int qbase = qb * 128 + wave * 32;
    int ntiles = 2 * qb + 2;             // always >= 2

    // staging: row = tid>>3 (0..31) and +32; pre-swizzled global source
    int srow = tid >> 3;
    int schs = ((tid & 7) ^ (srow & 7)) * 8;
    const unsigned short* kps = kb0 + (size_t)srow * rs + schs;
    const unsigned short* vps = vtb + (size_t)srow * T_ + schs;
    unsigned short* kdst = &Ks[0][0][0] + wave * 512;   // +buf*4096 u16
    unsigned short* vdst = &Vs[0][0][0] + wave * 512;

    auto STAGE = [&](int kt, int buf) {
        const unsigned short* ks = kps + (size_t)(kt * 64) * rs;
        const unsigned short* vs = vps + kt * 64;
        unsigned short* kd = kdst + buf * 4096;
        unsigned short* vd = vdst + buf * 4096;
        gl_lds16(ks, kd);
        gl_lds16(ks + (size_t)32 * rs, kd + 2048);
        gl_lds16(vs, vd);
        gl_lds16(vs + (size_t)32 * T_, vd + 2048);
    };

    // read-side swizzled chunk offsets (row&7 == m16&7 for all our rows)
    int kpc0 = ((0 + quad) ^ (m16 & 7)) << 3;
    int kpc1 = ((4 + quad) ^ (m16 & 7)) << 3;

    STAGE(0, 0);
    asm volatile("s_waitcnt vmcnt(0)" ::: "memory");
    __builtin_amdgcn_s_barrier();

    for (int kt = 0; kt < ntiles; ++kt) {
        int cur = kt & 1;
        if (kt + 1 < ntiles) STAGE(kt + 1, cur ^ 1);

        // ---- QK^T swapped: S^T[key][q]; lane: q = m16, key = st*16+quad*4+r
        f32x4 s[2][4];
        #pragma unroll
        for (int st = 0; st < 4; ++st) {
            bf16x8 k0 = *(const bf16x8*)&Ks[cur][st * 16 + m16][kpc0];
            bf16x8 k1 = *(const bf16x8*)&Ks[cur][st * 16 + m16][kpc1];
            __builtin_amdgcn_s_setprio(1);
            #pragma unroll
            for (int f = 0; f < 2; ++f) {
                f32x4 a = (f32x4){0.f, 0.f, 0.f, 0.f};
                a = __builtin_amdgcn_mfma_f32_16x16x32_bf16(k0, qf0[f], a, 0, 0, 0);
                a = __builtin_amdgcn_mfma_f32_16x16x32_bf16(k1, qf1[f], a, 0, 0, 0);
                s[f][st] = a;
            }
            __builtin_amdgcn_s_setprio(0);
        }

        // ---- causal mask (transposed indexing) ----
        if (kt >= 2 * qb) {
            #pragma unroll
            for (int f = 0; f < 2; ++f) {
                int qg = qbase + f * 16 + m16;
                #pragma unroll
                for (int st = 0; st < 4; ++st) {
                    int kg = kt * 64 + st * 16 + quad * 4;
                    #pragma unroll
                    for (int r = 0; r < 4; ++r)
                        if (kg + r > qg) s[f][st][r] = -1.0e30f;
                }
            }
        }

        // ---- exp2 + pack + scatter to P2 (16 cvt_pk + 16 b32 writes) ----
        #pragma unroll
        for (int f = 0; f < 2; ++f)
            #pragma unroll
            for (int st = 0; st < 4; ++st) {
                float p0 = exp2_fast(s[f][st][0]);
                float p1 = exp2_fast(s[f][st][1]);
                float p2 = exp2_fast(s[f][st][2]);
                float p3 = exp2_fast(s[f][st][3]);
                lrow[f] += (p0 + p1) + (p2 + p3);
                unsigned int d0 = cvt_pk_bf16(p0, p1);
                unsigned int d1 = cvt_pk_bf16(p2, p3);
                int pb = (st * 2 + (quad >> 1)) ^ (m16 & 7);
                int wd = (quad & 1) * 2;
                *(unsigned int*)&P2[wave][f][m16][pb * 8 + wd * 2]       = d0;
                *(unsigned int*)&P2[wave][f][m16][pb * 8 + (wd + 1) * 2] = d1;
            }
        __builtin_amdgcn_sched_barrier(0);

        // ---- PV: o[f] += P[f] @ V (pa read offset == V read offset) ----
        #pragma unroll
        for (int s2 = 0; s2 < 2; ++s2) {
            int pc = ((s2 * 4 + quad) ^ (m16 & 7)) << 3;
            #pragma unroll
            for (int f = 0; f < 2; ++f) {
                bf16x8 pa = *(const bf16x8*)&P2[wave][f][m16][pc];
                __builtin_amdgcn_s_setprio(1);
                #pragma unroll
                for (int dt = 0; dt < 4; ++dt) {
                    bf16x8 vv = *(const bf16x8*)&Vs[cur][dt * 16 + m16][pc];
                    o[f][dt] = __builtin_amdgcn_mfma_f32_16x16x32_bf16(
                        pa, vv, o[f][dt], 0, 0, 0);
                }
                __builtin_amdgcn_s_setprio(0);
            }
        }
        __builtin_amdgcn_sched_barrier(0);

        asm volatile("s_waitcnt vmcnt(0)" ::: "memory");
        __builtin_amdgcn_s_barrier();
    }

    // ---- finalize: quad-reduce denominators, redistribute, scale, store ----
    #pragma unroll
    for (int f = 0; f < 2; ++f) {
        float lf = lrow[f];
        lf += __shfl_xor(lf, 16);
        lf += __shfl_xor(lf, 32);          // full sum for q = m16 at every lane
        float inv = 1.0f / lf;
        #pragma unroll
        for (int r = 0; r < 4; ++r) {
            float invr = __shfl(inv, quad * 4 + r);   // inv for q-local quad*4+r
            unsigned short* op = base + (size_t)(qbase + f * 16 + quad * 4 + r) * rs;
            #pragma unroll
            for (int dt = 0; dt < 4; ++dt)
                op[dt * 16 + m16] = f2bf_hw(o[f][dt][r] * invr);
        }
    }
}

// ---------------------------------------------------------------------------
extern "C" void kernel_launch(void* const* d_in, const int* in_sizes, int n_in,
                              void* d_out, int out_size, void* d_ws, size_t ws_size,
                              hipStream_t stream) {
    const float* x      = (const float*)d_in[0];
    const float* w_attn = (const float*)d_in[1];
    const float* b_attn = (const float*)d_in[2];
    const float* w_proj = (const float*)d_in[3];
    const float* b_proj = (const float*)d_in[4];
    float* out = (float*)d_out;

    unsigned short* ws = (unsigned short*)d_ws;
    unsigned short* xb       = ws;                               // [B*T][C]
    unsigned short* w_attn_t = xb + (size_t)B_ * T_ * C_;        // [3C][C]
    unsigned short* w_proj_t = w_attn_t + (size_t)3 * C_ * C_;   // [C][C]
    unsigned short* qkv      = w_proj_t + (size_t)C_ * C_;       // [bstep*T][2C]

    const size_t fixed_hw = (size_t)B_ * T_ * C_ + 4 * (size_t)C_ * C_;
    const size_t per_b_hw = (size_t)T_ * 2 * C_ + (size_t)H_ * 64 * T_; // qk + vt
    int bstep = (ws_size >= (fixed_hw + (size_t)B_ * per_b_hw) * sizeof(unsigned short))
                ? B_ : 1;

    int nx = B_ * T_ * C_;
    convert_f32_bf16<<<nx / 2048, 256, 0, stream>>>(x, xb, nx);
    transpose_f32_bf16<<<dim3(3 * C_ / 32, C_ / 32), dim3(32, 8), 0, stream>>>(
        w_attn, w_attn_t, C_, 3 * C_);
    transpose_f32_bf16<<<dim3(C_ / 32, C_ / 32), dim3(32, 8), 0, stream>>>(
        w_proj, w_proj_t, C_, C_);

    // q pre-scale: (1/sqrt(D)) * log2(e)  -> softmax via exp2, no max-sub
    const float QSCALE = 0.125f * 1.44269504088896341f;

    for (int b0 = 0; b0 < B_; b0 += bstep) {
        int M = bstep * T_;
        const unsigned short* xbb = xb + (size_t)b0 * T_ * C_;
        unsigned short* vt = qkv + (size_t)bstep * T_ * 2 * C_;  // [bstep*H][64][T]

        gemm_qkv<<<dim3(3 * C_ / BN, M / BM), 256, 0, stream>>>(
            xbb, w_attn_t, b_attn, qkv, vt, M, QSCALE);

        attn_mfma<<<dim3(bstep * H_, T_ / 128), 256, 0, stream>>>(qkv, vt);

        gemm_out<<<dim3(C_ / BN, M / BM), 256, 0, stream>>>(
            qkv, w_proj_t, b_proj, out + (size_t)b0 * T_ * C_, M);
    }
}